// Round 1
// baseline (637.107 us; speedup 1.0000x reference)
//
#include <hip/hip_runtime.h>

#define TILE 256

__global__ __launch_bounds__(256) void chamfer_min_dir_kernel(
    const float* __restrict__ A,   // "self" cloud  [BS][N][3]
    const float* __restrict__ B,   // "other" cloud [BS][M][3]
    float* __restrict__ sum_out,   // single accumulator (sum of sqrt(min d^2))
    int N, int M)
{
    const int b = blockIdx.y;
    const int i = blockIdx.x * TILE + threadIdx.x;   // grid sized exactly
    const float* Ab = A + (size_t)b * N * 3;
    const float* Bb = B + (size_t)b * M * 3;

    const float px = Ab[i * 3 + 0];
    const float py = Ab[i * 3 + 1];
    const float pz = Ab[i * 3 + 2];

    float mind = 3.4e38f;

    __shared__ float4 tile[TILE];

    for (int j0 = 0; j0 < M; j0 += TILE) {
        const int j = j0 + threadIdx.x;
        // stage other-cloud tile into LDS as float4 (pad for ds_read_b128)
        const float gx = Bb[j * 3 + 0];
        const float gy = Bb[j * 3 + 1];
        const float gz = Bb[j * 3 + 2];
        __syncthreads();                 // previous tile fully consumed
        tile[threadIdx.x] = make_float4(gx, gy, gz, 0.0f);
        __syncthreads();                 // tile fully written

        #pragma unroll 8
        for (int jj = 0; jj < TILE; ++jj) {
            const float4 g = tile[jj];   // broadcast read, conflict-free
            const float dx = px - g.x;
            const float dy = py - g.y;
            const float dz = pz - g.z;
            float d = dx * dx;
            d = fmaf(dy, dy, d);
            d = fmaf(dz, dz, d);
            mind = fminf(mind, d);
        }
    }

    float v = sqrtf(mind);

    // wave(64) shuffle reduction
    for (int off = 32; off > 0; off >>= 1)
        v += __shfl_down(v, off);

    __shared__ float wsum[TILE / 64];
    if ((threadIdx.x & 63) == 0)
        wsum[threadIdx.x >> 6] = v;
    __syncthreads();
    if (threadIdx.x == 0) {
        float s = 0.0f;
        #pragma unroll
        for (int w = 0; w < TILE / 64; ++w) s += wsum[w];
        atomicAdd(sum_out, s);
    }
}

__global__ void chamfer_finalize_kernel(const float* __restrict__ sums,
                                        float* __restrict__ out,
                                        float scale)
{
    const float p2g = sums[0] * scale;
    const float g2p = sums[1] * scale;
    out[0] = p2g + g2p;   // mean loss
    out[1] = p2g;         // mean p2g
    out[2] = g2p;         // mean g2p
}

extern "C" void kernel_launch(void* const* d_in, const int* in_sizes, int n_in,
                              void* d_out, int out_size, void* d_ws, size_t ws_size,
                              hipStream_t stream) {
    const float* points = (const float*)d_in[0];   // [32][4096][3]
    const float* gts    = (const float*)d_in[1];   // [32][4096][3]
    float* out = (float*)d_out;
    float* ws  = (float*)d_ws;

    const int BS = 32, N = 4096, M = 4096;

    hipMemsetAsync(d_ws, 0, 2 * sizeof(float), stream);

    dim3 grid(N / TILE, BS);
    chamfer_min_dir_kernel<<<grid, TILE, 0, stream>>>(points, gts, ws + 0, N, M);
    chamfer_min_dir_kernel<<<grid, TILE, 0, stream>>>(gts, points, ws + 1, M, N);

    const float scale = 1.0f / (float)(BS * N);
    chamfer_finalize_kernel<<<1, 1, 0, stream>>>(ws, out, scale);
}

// Round 2
// 107.424 us; speedup vs baseline: 5.9308x; 5.9308x over previous
//
#include <hip/hip_runtime.h>

#define BLOCK 256
#define P 4              // A-points per thread
#define SUB 64           // B-subtile points per staging round
#define NWAVE 4          // waves per block; each wave owns one j-slice

__global__ __launch_bounds__(256) void chamfer_kernel(
    const float* __restrict__ points,   // [BS][N][3]
    const float* __restrict__ gts,      // [BS][N][3]
    float* __restrict__ sums,           // [2] accumulators
    int N)
{
    const int b   = blockIdx.y;
    const int dir = blockIdx.z;
    const float* A = dir ? gts    : points;   // "self" cloud
    const float* B = dir ? points : gts;      // "other" cloud

    const int w = threadIdx.x >> 6;   // wave id 0..3
    const int l = threadIdx.x & 63;   // lane id

    const float* Ab = A + (size_t)b * N * 3;
    const float* Bb = B + (size_t)b * N * 3;

    const int pbase = blockIdx.x * BLOCK;

    // Each thread owns P=4 A-points; all 4 waves cover the SAME 256 points
    // but scan DIFFERENT quarters of B (j-split for occupancy).
    float ax[P], ay[P], az[P], ha[P], mind[P];
    #pragma unroll
    for (int p = 0; p < P; ++p) {
        const int i = pbase + p * 64 + l;
        ax[p] = Ab[i * 3 + 0];
        ay[p] = Ab[i * 3 + 1];
        az[p] = Ab[i * 3 + 2];
        ha[p] = 0.5f * (ax[p] * ax[p] + ay[p] * ay[p] + az[p] * az[p]);
        mind[p] = 3.4e38f;
    }

    __shared__ float4 tile[NWAVE][SUB];   // per-wave private subtile
    __shared__ float  pmin[NWAVE][BLOCK]; // cross-wave min combine

    const int slice = N / NWAVE;          // 1024
    const int jbase = w * slice;

    for (int r = 0; r < slice; r += SUB) {
        const int j = jbase + r + l;
        const float bx = Bb[j * 3 + 0];
        const float by = Bb[j * 3 + 1];
        const float bz = Bb[j * 3 + 2];
        const float hb = 0.5f * (bx * bx + by * by + bz * bz);
        tile[w][l] = make_float4(bx, by, bz, hb);
        __syncthreads();   // write→broadcast-read visibility (uniform flow)

        #pragma unroll 8
        for (int jj = 0; jj < SUB; ++jj) {
            const float4 g = tile[w][jj];   // wave-uniform broadcast read
            #pragma unroll
            for (int p = 0; p < P; ++p) {
                float t = fmaf(ax[p], g.x, -ha[p]);
                t = fmaf(ay[p], g.y, t);
                t = fmaf(az[p], g.z, t);
                const float q = g.w - t;          // (|a|^2+|b|^2)/2 - a.b = d^2/2
                mind[p] = fminf(mind[p], q);
            }
        }
        __syncthreads();   // all reads done before next round's overwrite
    }

    // combine the 4 waves' partial mins
    #pragma unroll
    for (int p = 0; p < P; ++p)
        pmin[w][p * 64 + l] = mind[p];
    __syncthreads();

    const int t = threadIdx.x;            // point pbase + t
    const float q = fminf(fminf(pmin[0][t], pmin[1][t]),
                          fminf(pmin[2][t], pmin[3][t]));
    float v = sqrtf(fmaxf(q + q, 0.0f));  // d = sqrt(2*q), clamped

    // block sum -> one atomic per block
    for (int off = 32; off > 0; off >>= 1)
        v += __shfl_down(v, off);

    __shared__ float wsum[NWAVE];
    if (l == 0) wsum[w] = v;
    __syncthreads();
    if (t == 0)
        atomicAdd(sums + dir, wsum[0] + wsum[1] + wsum[2] + wsum[3]);
}

__global__ void chamfer_finalize_kernel(const float* __restrict__ sums,
                                        float* __restrict__ out,
                                        float scale)
{
    const float p2g = sums[0] * scale;
    const float g2p = sums[1] * scale;
    out[0] = p2g + g2p;   // mean loss
    out[1] = p2g;         // mean p2g
    out[2] = g2p;         // mean g2p
}

extern "C" void kernel_launch(void* const* d_in, const int* in_sizes, int n_in,
                              void* d_out, int out_size, void* d_ws, size_t ws_size,
                              hipStream_t stream) {
    const float* points = (const float*)d_in[0];   // [32][4096][3]
    const float* gts    = (const float*)d_in[1];   // [32][4096][3]
    float* out = (float*)d_out;
    float* ws  = (float*)d_ws;

    const int BS = 32, N = 4096;

    hipMemsetAsync(d_ws, 0, 2 * sizeof(float), stream);

    dim3 grid(N / BLOCK, BS, 2);
    chamfer_kernel<<<grid, BLOCK, 0, stream>>>(points, gts, ws, N);

    const float scale = 1.0f / (float)(BS * N);
    chamfer_finalize_kernel<<<1, 1, 0, stream>>>(ws, out, scale);
}